// Round 6
// baseline (232.666 us; speedup 1.0000x reference)
//
#include <hip/hip_runtime.h>

#define N_NODES 100000
#define N_EDGES 800000
#define DIM 64
#define HEADS 4

#define SCAN_BLK 256
#define N_SCAN_BLOCKS ((N_NODES + SCAN_BLK - 1) / SCAN_BLK)   // 391

typedef __attribute__((ext_vector_type(8))) short bf16x8;
typedef __attribute__((ext_vector_type(4))) float f32x4;

__device__ __forceinline__ short f2bf(float x) {
    union { float f; unsigned u; } v; v.f = x;
    unsigned r = (v.u + 0x7FFFu + ((v.u >> 16) & 1u)) >> 16;   // RNE
    return (short)r;
}
__device__ __forceinline__ float bf2f(short b) {
    union { float f; unsigned u; } v; v.u = ((unsigned)(unsigned short)b) << 16;
    return v.f;
}

// ---------------------------------------------------------------------------
// wprep: pack [Wq|Wk|Wv] (64x192) into MFMA B-fragment order, hi+lo bf16.
// ---------------------------------------------------------------------------
__global__ __launch_bounds__(256) void wprep_kernel(
    const float* __restrict__ Wq, const float* __restrict__ Wk,
    const float* __restrict__ Wv,
    short* __restrict__ wfragH, short* __restrict__ wfragL)
{
    const int idx = blockIdx.x * 256 + threadIdx.x;
    if (idx >= 12288) return;
    const int j    = idx & 7;
    const int lane = (idx >> 3) & 63;
    const int kt   = (idx >> 9) & 1;
    const int nt   = idx >> 10;
    const int k      = kt * 32 + (lane >> 4) * 8 + j;
    const int col192 = nt * 16 + (lane & 15);
    const float* W = (col192 < 64) ? Wq : ((col192 < 128) ? Wk : Wv);
    const float x = W[k * DIM + (col192 & 63)];
    const short hb = f2bf(x);
    wfragH[idx] = hb;
    wfragL[idx] = f2bf(x - bf2f(hb));
}

// ---------------------------------------------------------------------------
// qkv via MFMA, bf16x3 split. Q stored fp32; K,V stored bf16.
// ---------------------------------------------------------------------------
__global__ __launch_bounds__(256) void qkv_mfma_kernel(
    const float* __restrict__ embeds,
    const short* __restrict__ wfragH,
    const short* __restrict__ wfragL,
    float* __restrict__ Q,
    unsigned short* __restrict__ Kb,
    unsigned short* __restrict__ Vb)
{
    __shared__ __align__(16) short sBH[12288];
    __shared__ __align__(16) short sBL[12288];

    const int t = threadIdx.x;
    {
        const int4* srcH = (const int4*)wfragH;
        const int4* srcL = (const int4*)wfragL;
        int4* dH = (int4*)sBH; int4* dL = (int4*)sBL;
        #pragma unroll
        for (int i = 0; i < 6; ++i) {
            dH[t + 256 * i] = srcH[t + 256 * i];
            dL[t + 256 * i] = srcL[t + 256 * i];
        }
    }
    __syncthreads();

    const int lane = t & 63;
    const int wid  = t >> 6;
    const int m0 = blockIdx.x * 64 + wid * 16;

    int arow = m0 + (lane & 15);
    if (arow >= N_NODES) arow = N_NODES - 1;       // clamp; store is guarded
    const float* ap = embeds + (size_t)arow * DIM + ((lane >> 4) * 8);

    bf16x8 aH[2], aL[2];
    #pragma unroll
    for (int kt = 0; kt < 2; ++kt) {
        const float4 x0 = ((const float4*)(ap + kt * 32))[0];
        const float4 x1 = ((const float4*)(ap + kt * 32))[1];
        const float xs[8] = {x0.x, x0.y, x0.z, x0.w, x1.x, x1.y, x1.z, x1.w};
        bf16x8 h8, l8;
        #pragma unroll
        for (int j = 0; j < 8; ++j) {
            const short hb = f2bf(xs[j]);
            h8[j] = hb;
            l8[j] = f2bf(xs[j] - bf2f(hb));
        }
        aH[kt] = h8; aL[kt] = l8;
    }

    f32x4 acc[12];
    #pragma unroll
    for (int nt = 0; nt < 12; ++nt) acc[nt] = (f32x4){0.f, 0.f, 0.f, 0.f};

    #pragma unroll
    for (int kt = 0; kt < 2; ++kt) {
        #pragma unroll
        for (int nt = 0; nt < 12; ++nt) {
            const int o = ((nt * 2 + kt) * 64 + lane) * 8;
            const bf16x8 bH = *(const bf16x8*)(sBH + o);
            const bf16x8 bL = *(const bf16x8*)(sBL + o);
            acc[nt] = __builtin_amdgcn_mfma_f32_16x16x32_bf16(aH[kt], bH, acc[nt], 0, 0, 0);
            acc[nt] = __builtin_amdgcn_mfma_f32_16x16x32_bf16(aH[kt], bL, acc[nt], 0, 0, 0);
            acc[nt] = __builtin_amdgcn_mfma_f32_16x16x32_bf16(aL[kt], bH, acc[nt], 0, 0, 0);
        }
    }

    // C/D layout: col = lane&15, row = m0 + (lane>>4)*4 + reg
    const int rbase = m0 + (lane >> 4) * 4;
    const int cl = lane & 15;
    #pragma unroll
    for (int nt = 0; nt < 12; ++nt) {
        const int col192 = nt * 16 + cl;
        #pragma unroll
        for (int r = 0; r < 4; ++r) {
            const int row = rbase + r;
            if (row < N_NODES) {
                if (col192 < 64)
                    Q[(size_t)row * DIM + col192] = acc[nt][r];
                else if (col192 < 128)
                    Kb[(size_t)row * DIM + (col192 - 64)] = (unsigned short)f2bf(acc[nt][r]);
                else
                    Vb[(size_t)row * DIM + (col192 - 128)] = (unsigned short)f2bf(acc[nt][r]);
            }
        }
    }
}

// ---------------------------------------------------------------------------
// CSR: hist (+rank) -> scanA -> scanC (absorbs top-level scan) -> scatter
// ---------------------------------------------------------------------------
__global__ __launch_bounds__(256) void hist_kernel(
    const int* __restrict__ rows, int* __restrict__ counts,
    int* __restrict__ rank)
{
    const int e = blockIdx.x * 256 + threadIdx.x;
    if (e < N_EDGES) rank[e] = atomicAdd(&counts[rows[e]], 1);
}

__global__ __launch_bounds__(SCAN_BLK) void scanA_kernel(
    const int* __restrict__ counts, int* __restrict__ blockSums)
{
    __shared__ int tile[SCAN_BLK];
    const int i = blockIdx.x * SCAN_BLK + threadIdx.x;
    tile[threadIdx.x] = (i < N_NODES) ? counts[i] : 0;
    __syncthreads();
    for (int off = SCAN_BLK / 2; off > 0; off >>= 1) {
        if (threadIdx.x < off) tile[threadIdx.x] += tile[threadIdx.x + off];
        __syncthreads();
    }
    if (threadIdx.x == 0) blockSums[blockIdx.x] = tile[0];
}

// scanC: each block scans the 391 blockSums in LDS (pair-packed Hillis-Steele)
// to get its own prefix, then local-scans its counts tile. No scanB dispatch.
__global__ __launch_bounds__(SCAN_BLK) void scanC_kernel(
    const int* __restrict__ counts,
    const int* __restrict__ blockSums,
    int* __restrict__ offsets)
{
    __shared__ int pairs[256];
    __shared__ int tile[SCAN_BLK];
    __shared__ int sPrefix;
    const int t = threadIdx.x;

    const int i0 = 2 * t, i1 = 2 * t + 1;
    const int a = (i0 < N_SCAN_BLOCKS) ? blockSums[i0] : 0;
    const int b = (i1 < N_SCAN_BLOCKS) ? blockSums[i1] : 0;
    pairs[t] = a + b;
    __syncthreads();
    for (int off = 1; off < 256; off <<= 1) {
        const int add = (t >= off) ? pairs[t - off] : 0;
        __syncthreads();
        pairs[t] += add;
        __syncthreads();
    }
    if (t == (blockIdx.x >> 1)) {
        const int pexcl = pairs[t] - (a + b);          // exclusive pair prefix
        sPrefix = pexcl + ((blockIdx.x & 1) ? a : 0);
    }

    const int i = blockIdx.x * SCAN_BLK + t;
    const int v = (i < N_NODES) ? counts[i] : 0;
    tile[t] = v;
    __syncthreads();
    for (int off = 1; off < SCAN_BLK; off <<= 1) {
        const int add = (t >= off) ? tile[t - off] : 0;
        __syncthreads();
        tile[t] += add;
        __syncthreads();
    }
    if (i < N_NODES) offsets[i] = tile[t] - v + sPrefix;
}

__global__ __launch_bounds__(256) void scatter_kernel(
    const int* __restrict__ rows,
    const int* __restrict__ cols,
    const int* __restrict__ offsets,
    const int* __restrict__ rank,
    int* __restrict__ sortedCol,     // [E] CSR order (4B random write)
    int* __restrict__ posArr)        // [E] edge -> CSR slot (coalesced write)
{
    const int e = blockIdx.x * 256 + threadIdx.x;
    if (e < N_EDGES) {
        const int pos = offsets[rows[e]] + rank[e];
        sortedCol[pos] = cols[e];
        posArr[e] = pos;
    }
}

// ---------------------------------------------------------------------------
// Fused per-node aggregation: 1 wave/node, 8 edges/iter with split dots.
// lane = half*32 + slot*4 + h. Each (edge,head) dot = 2 lanes x 8 elems +
// shfl_xor(32). expAtt written COALESCED in CSR order. Zero atomics.
// ---------------------------------------------------------------------------
__global__ __launch_bounds__(256) void node_agg_kernel(
    const float* __restrict__ Q,
    const unsigned short* __restrict__ Kb,
    const unsigned short* __restrict__ Vb,
    const int* __restrict__ offsets,
    const int* __restrict__ counts,
    const int* __restrict__ sortedCol,
    float* __restrict__ expCsr,      // [E,4] expAtt in CSR slot order
    float* __restrict__ normArr,     // [N,4]
    float* __restrict__ res)         // [N,64]
{
    const int node = (blockIdx.x * 256 + threadIdx.x) >> 6;
    const int lane = threadIdx.x & 63;
    if (node >= N_NODES) return;

    const int start = offsets[node];
    const int cnt   = counts[node];

    const int h    = lane & 3;         // head for QK phase
    const int slot = (lane >> 2) & 7;  // edge slot 0..7
    const int half = lane >> 5;        // which 8 of the 16 dot elements
    const int hd   = lane >> 4;        // head owning dim=lane in PV phase

    float qv[8];
    {
        const float4* qp = (const float4*)(Q + (size_t)node * DIM + h * 16 + half * 8);
        ((float4*)qv)[0] = qp[0];
        ((float4*)qv)[1] = qp[1];
    }

    float normacc = 0.0f;
    float acc     = 0.0f;

    for (int cb = 0; cb < cnt; cb += 8) {
        const int jj = cb + slot;
        const bool active = (jj < cnt);
        int col = 0;
        if (active) col = sortedCol[start + jj];

        // half-dot over 8 elems, completed by cross-half shfl_xor
        const bf16x8 k8 = *(const bf16x8*)(Kb + (size_t)col * DIM + h * 16 + half * 8);
        float s = 0.0f;
        #pragma unroll
        for (int j = 0; j < 8; ++j) s = fmaf(qv[j], bf2f(k8[j]), s);
        s += __shfl_xor(s, 32, 64);
        s = fminf(fmaxf(s, -10.0f), 10.0f);
        const float ex = active ? __expf(s) : 0.0f;
        if (active && half == 0) expCsr[(size_t)(start + jj) * HEADS + h] = ex;
        normacc += ex;   // both halves identical; reduced over slots only

        // PV: 8 edges; V loads issued first (8 outstanding), then FMAs
        unsigned short raw[8];
        #pragma unroll
        for (int s2 = 0; s2 < 8; ++s2) {
            const int c2 = __builtin_amdgcn_readlane(col, s2 * 4);
            raw[s2] = Vb[(size_t)c2 * DIM + lane];
        }
        #pragma unroll
        for (int s2 = 0; s2 < 8; ++s2) {
            acc = fmaf(__shfl(ex, s2 * 4 + hd, 64), bf2f((short)raw[s2]), acc);
        }
    }

    // reduce over slot bits (2,3,4); halves already hold identical sums
    #pragma unroll
    for (int m2 = 4; m2 <= 16; m2 <<= 1)
        normacc += __shfl_xor(normacc, m2, 64);
    // lane holds total norm for head h = lane&3

    if (lane < 4) normArr[(size_t)node * HEADS + lane] = normacc;

    const float nrm = __shfl(normacc, hd, 64);
    res[(size_t)node * DIM + lane] = acc / (nrm + 1e-8f);
}

// ---------------------------------------------------------------------------
// Edge-parallel normalization: gather expCsr[pos[e]] (16B), write att (16B).
// ---------------------------------------------------------------------------
__global__ __launch_bounds__(256) void norm_edge_kernel(
    const int* __restrict__ rows,
    const int* __restrict__ posArr,
    const float* __restrict__ expCsr,
    const float* __restrict__ normArr,
    float* __restrict__ attOut)
{
    const int e = blockIdx.x * 256 + threadIdx.x;
    if (e >= N_EDGES) return;
    const int p = posArr[e];
    float4 ex4 = ((const float4*)expCsr)[p];
    const float4 n4 = ((const float4*)normArr)[rows[e]];
    ex4.x /= (n4.x + 1e-8f);
    ex4.y /= (n4.y + 1e-8f);
    ex4.z /= (n4.z + 1e-8f);
    ex4.w /= (n4.w + 1e-8f);
    ((float4*)attOut)[e] = ex4;
}

// ---------------------------------------------------------------------------

extern "C" void kernel_launch(void* const* d_in, const int* in_sizes, int n_in,
                              void* d_out, int out_size, void* d_ws, size_t ws_size,
                              hipStream_t stream) {
    const float* embeds = (const float*)d_in[0];
    const float* Wq     = (const float*)d_in[1];
    const float* Wk     = (const float*)d_in[2];
    const float* Wv     = (const float*)d_in[3];
    const int*   rows   = (const int*)d_in[4];
    const int*   cols   = (const int*)d_in[5];

    float* out    = (float*)d_out;
    float* res    = out;                                 // [N, 64]
    float* attOut = out + (size_t)N_NODES * DIM;         // [E, 4]

    float*          Q         = (float*)d_ws;                                   // [N,64] f32
    unsigned short* Kb        = (unsigned short*)(Q + (size_t)N_NODES * DIM);   // [N,64] bf16
    unsigned short* Vb        = Kb + (size_t)N_NODES * DIM;                     // [N,64] bf16
    float*          expCsr    = (float*)(Vb + (size_t)N_NODES * DIM);           // [E,4]
    float*          normArr   = expCsr + (size_t)N_EDGES * HEADS;               // [N,4]
    int*            sortedCol = (int*)(normArr + (size_t)N_NODES * HEADS);      // [E]
    int*            posArr    = sortedCol + N_EDGES;                            // [E]
    int*            rank      = posArr + N_EDGES;                               // [E]
    int*            counts    = rank + N_EDGES;                                 // [N]
    int*            offsets   = counts + N_NODES;                               // [N]
    int*            blockSums = offsets + N_NODES;                              // [512]
    short*          wfragH    = (short*)(blockSums + 512);                      // [12288]
    short*          wfragL    = wfragH + 12288;                                 // [12288]

    hipMemsetAsync(counts, 0, (size_t)N_NODES * sizeof(int), stream);

    wprep_kernel<<<48, 256, 0, stream>>>(Wq, Wk, Wv, wfragH, wfragL);
    qkv_mfma_kernel<<<(N_NODES + 63) / 64, 256, 0, stream>>>(embeds, wfragH, wfragL, Q, Kb, Vb);

    const int eblocks = (N_EDGES + 255) / 256;
    hist_kernel<<<eblocks, 256, 0, stream>>>(rows, counts, rank);
    scanA_kernel<<<N_SCAN_BLOCKS, SCAN_BLK, 0, stream>>>(counts, blockSums);
    scanC_kernel<<<N_SCAN_BLOCKS, SCAN_BLK, 0, stream>>>(counts, blockSums, offsets);
    scatter_kernel<<<eblocks, 256, 0, stream>>>(rows, cols, offsets, rank, sortedCol, posArr);

    const int nblocks = (N_NODES * 64 + 255) / 256;      // 1 wave per node
    node_agg_kernel<<<nblocks, 256, 0, stream>>>(Q, Kb, Vb, offsets, counts,
                                                 sortedCol, expCsr, normArr, res);

    norm_edge_kernel<<<eblocks, 256, 0, stream>>>(rows, posArr, expCsr, normArr, attOut);
}